// Round 1
// baseline (433.797 us; speedup 1.0000x reference)
//
#include <hip/hip_runtime.h>

// 3x3 conv, stride 1, pad 1, NCHW, C=1. eff_w[i][j] = weight[i][j]*kx[i]*kx[j],
// kx = [den, 1, den]. x: (16,1,2048,2048) fp32 -> out same shape fp32.
//
// Memory-bound stencil: each thread computes a 4(w) x 8(h) output tile.
// Vertical reuse via 3 sliding row-register buffers (read amp = 10/8 = 1.25x).
// Horizontal halo: 2 scalar edge loads per row (L1 hits).

#define IMG_W 2048
#define IMG_H 2048
#define BATCH 16
#define RPT 8                  // rows per thread
#define WCHUNKS (IMG_W / 4)    // 512 float4 chunks per row
#define ROWGRPS (IMG_H / RPT)  // 256 row-groups

__global__ __launch_bounds__(256) void conv3x3_kernel(
    const float* __restrict__ x,
    const float* __restrict__ weight,
    const float* __restrict__ den,
    float* __restrict__ out)
{
    const int tid    = blockIdx.x * 256 + threadIdx.x;
    const int wchunk = tid & (WCHUNKS - 1);        // 9 bits
    const int rowgrp = (tid >> 9) & (ROWGRPS - 1); // 8 bits
    const int b      = tid >> 17;

    // effective 3x3 weights (scalar loads broadcast; cheap)
    const float d = den[0];
    const float k[3] = {d, 1.0f, d};
    float wgt[3][3];
#pragma unroll
    for (int i = 0; i < 3; ++i)
#pragma unroll
        for (int j = 0; j < 3; ++j)
            wgt[i][j] = weight[i * 3 + j] * k[i] * k[j];

    const float* xb = x   + (size_t)b * IMG_H * IMG_W;
    float*       ob = out + (size_t)b * IMG_H * IMG_W;
    const int w0 = wchunk * 4;
    const int h0 = rowgrp * RPT;
    const bool has_l = (w0 > 0);
    const bool has_r = (w0 + 4 < IMG_W);

    // row buffer layout: v[0]=col w0-1, v[1..4]=cols w0..w0+3, v[5]=col w0+4
    auto load_row = [&](int h, float v[6]) {
        if (h < 0 || h >= IMG_H) {
#pragma unroll
            for (int i = 0; i < 6; ++i) v[i] = 0.0f;
            return;
        }
        const float* r = xb + (size_t)h * IMG_W + w0;
        const float4 c = *(const float4*)r;
        v[1] = c.x; v[2] = c.y; v[3] = c.z; v[4] = c.w;
        v[0] = has_l ? r[-1] : 0.0f;
        v[5] = has_r ? r[4]  : 0.0f;
    };

    float ra[6], rb[6], rc[6];
    load_row(h0 - 1, ra);  // h0==0 -> zeros (top padding)
    load_row(h0,     rb);

#pragma unroll
    for (int rr = 0; rr < RPT; ++rr) {
        load_row(h0 + rr + 1, rc);  // bottom padding handled inside

        float4 o;
        float* op = &o.x;
#pragma unroll
        for (int j = 0; j < 4; ++j) {
            op[j] = wgt[0][0]*ra[j] + wgt[0][1]*ra[j+1] + wgt[0][2]*ra[j+2]
                  + wgt[1][0]*rb[j] + wgt[1][1]*rb[j+1] + wgt[1][2]*rb[j+2]
                  + wgt[2][0]*rc[j] + wgt[2][1]*rc[j+1] + wgt[2][2]*rc[j+2];
        }
        *(float4*)(ob + (size_t)(h0 + rr) * IMG_W + w0) = o;

#pragma unroll
        for (int i = 0; i < 6; ++i) { ra[i] = rb[i]; rb[i] = rc[i]; }
    }
}

extern "C" void kernel_launch(void* const* d_in, const int* in_sizes, int n_in,
                              void* d_out, int out_size, void* d_ws, size_t ws_size,
                              hipStream_t stream) {
    const float* x      = (const float*)d_in[0];
    const float* weight = (const float*)d_in[1];
    const float* den    = (const float*)d_in[2];
    float*       out    = (float*)d_out;

    const int total  = WCHUNKS * ROWGRPS * BATCH;  // 2,097,152 threads
    const int blocks = total / 256;                // 8192
    conv3x3_kernel<<<blocks, 256, 0, stream>>>(x, weight, den, out);
}